// Round 8
// baseline (1077.257 us; speedup 1.0000x reference)
//
#include <hip/hip_runtime.h>
#include <stdint.h>

// LatentODE fused: B=8192, T=100, D=44, NH=64, L=8.
// 256 blocks x 128 thr. Each block owns 32 samples = TWO 16-col tiles.
// Wave0 runs TWO independent serial chains (RNN scan, z0/KL, RK4) fully
// interleaved in-register: each chain's issue fills the other's MFMA/trans/
// memory latency gaps (rounds 5-6 showed single-chain latency is the wall;
// stalls ~45%/SIMD). Weights shared across tiles; only state doubles.
// Wave1 = decoder+NLL for both tiles via LDS ring (unchanged protocol).
// Per-tile math bit-identical to round 6.
// (Resubmission: round-7 bench died at container level, no kernel signal.)

constexpr int B_ = 8192, T_ = 100, D_ = 44, NH_ = 64, L_ = 8;

typedef float f32x4 __attribute__((ext_vector_type(4)));
typedef uint32_t u32x2 __attribute__((ext_vector_type(2)));

// ---- K=16 MFMA with __has_builtin fallback chain ----
#if __has_builtin(__builtin_amdgcn_mfma_f32_16x16x16bf16_1k)
typedef short frag16 __attribute__((ext_vector_type(4)));
#define MFMA16(a, b, c) __builtin_amdgcn_mfma_f32_16x16x16bf16_1k(a, b, c, 0, 0, 0)
#define USE_F16 0
#elif __has_builtin(__builtin_amdgcn_mfma_f32_16x16x16_bf16_1k)
typedef short frag16 __attribute__((ext_vector_type(4)));
#define MFMA16(a, b, c) __builtin_amdgcn_mfma_f32_16x16x16_bf16_1k(a, b, c, 0, 0, 0)
#define USE_F16 0
#elif __has_builtin(__builtin_amdgcn_mfma_f32_16x16x16_bf16)
typedef __bf16 frag16 __attribute__((ext_vector_type(4)));
#define MFMA16(a, b, c) __builtin_amdgcn_mfma_f32_16x16x16_bf16(a, b, c, 0, 0, 0)
#define USE_F16 0
#else
typedef _Float16 frag16 __attribute__((ext_vector_type(4)));
#define MFMA16(a, b, c) __builtin_amdgcn_mfma_f32_16x16x16f16(a, b, c, 0, 0, 0)
#define USE_F16 1
#endif

__device__ __forceinline__ float fexp2(float x) { return __builtin_amdgcn_exp2f(x); }
__device__ __forceinline__ float frcp(float x) { return __builtin_amdgcn_rcpf(x); }
__device__ __forceinline__ float fexp(float x) { return fexp2(x * 1.44269504088896341f); }
__device__ __forceinline__ float tanh_f(float x) {
  float e = fexp2(x * 2.88539008177792681f);
  return 1.0f - 2.0f * frcp(e + 1.0f);
}
__device__ __forceinline__ float elu_f(float x) { return x > 0.0f ? x : (fexp(x) - 1.0f); }

__device__ __forceinline__ uint32_t EW(float v) {
#if USE_F16
  return (uint32_t)__builtin_bit_cast(unsigned short, (_Float16)v);
#else
  return (uint32_t)__builtin_bit_cast(unsigned short, (__bf16)v);
#endif
}
__device__ __forceinline__ uint32_t PK2(float lo, float hi) { return EW(lo) | (EW(hi) << 16); }
__device__ __forceinline__ frag16 fr4(float a, float b, float c, float d) {
  u32x2 u = {PK2(a, b), PK2(c, d)};
  return __builtin_bit_cast(frag16, u);
}
__device__ __forceinline__ frag16 frpk(f32x4 v) {
  u32x2 u = {PK2(v[0], v[1]), PK2(v[2], v[3])};
  return __builtin_bit_cast(frag16, u);
}
__device__ __forceinline__ float f4get(const float4& f, int i) {
  return i == 0 ? f.x : (i == 1 ? f.y : (i == 2 ? f.z : f.w));
}

__global__ __launch_bounds__(128) void fused_kernel(
    const float* __restrict__ x, const float* __restrict__ mask,
    const float* __restrict__ eps,
    const float* __restrict__ Wi2h, const float* __restrict__ bi2h,
    const float* __restrict__ Wh2o, const float* __restrict__ bh2o,
    const float* __restrict__ Wf1, const float* __restrict__ bf1,
    const float* __restrict__ Wf2, const float* __restrict__ bf2,
    const float* __restrict__ Wf3, const float* __restrict__ bf3,
    const float* __restrict__ Wd1, const float* __restrict__ bd1,
    const float* __restrict__ Wd2, const float* __restrict__ bd2,
    float* __restrict__ part) {
  const int tid = threadIdx.x;
  const int wid = tid >> 6;
  const int lane = tid & 63;
  const int c = lane & 15, q = lane >> 4;
  const int r0 = blockIdx.x * 32;  // 2 tiles: rows r0+16*it+c
  const f32x4 fzero = {0.f, 0.f, 0.f, 0.f};

  // z-ring: [t][it][c*2+q] u32x2 (bf16-packed z rows 4q..4q+3), q<2.
  __shared__ __align__(16) uint32_t ring[12800];  // 100*2*32*2 u32 = 51.2 KB
  __shared__ uint32_t flags[104];
  __shared__ float sse_sh;

  if (tid < 104) flags[tid] = 0u;
  __syncthreads();

  float klt = 0.0f;

  if (wid == 0) {
    // ==================== WAVE 0: two serial chains ====================
    const frag16 fgbias = fr4(1.0f, 0.f, 0.f, 0.f);

    // ---- Phase 1 weights (shared across tiles) ----
    frag16 Ai[4][7];
#pragma unroll
    for (int tau = 0; tau < 4; ++tau)
#pragma unroll
      for (int kc = 0; kc < 7; ++kc) {
        const int m = 16 * tau + c;
        float wv[4];
#pragma unroll
        for (int i = 0; i < 4; ++i) {
          const int k = 16 * kc + 4 * q + i;
          float v = 0.0f;
          if (k < 64) v = Wi2h[(44 + k) * 64 + m];
          else if (k < 108) v = Wi2h[(k - 64) * 64 + m];
          else if (k == 108) v = bi2h[m];
          wv[i] = v;
        }
        Ai[tau][kc] = fr4(wv[0], wv[1], wv[2], wv[3]);
      }
    frag16 Ah2o[4];
#pragma unroll
    for (int kc = 0; kc < 4; ++kc) {
      float wv[4];
#pragma unroll
      for (int i = 0; i < 4; ++i) wv[i] = Wh2o[(16 * kc + 4 * q + i) * 16 + c];
      Ah2o[kc] = fr4(wv[0], wv[1], wv[2], wv[3]);
    }
    f32x4 bo;
#pragma unroll
    for (int r = 0; r < 4; ++r) bo[r] = bh2o[4 * q + r];

    const float* xrb[2], * mrb[2];
#pragma unroll
    for (int it = 0; it < 2; ++it) {
      xrb[it] = x + (size_t)(r0 + 16 * it + c) * T_ * D_;
      mrb[it] = mask + (size_t)(r0 + 16 * it + c) * T_ * D_;
    }

    auto load_obs = [&](int it, int t, float4* xv, float4* mv) {
      const float* xp = xrb[it] + (size_t)t * D_;
      const float* mp = mrb[it] + (size_t)t * D_;
      xv[0] = *(const float4*)(xp + 4 * q);
      mv[0] = *(const float4*)(mp + 4 * q);
      xv[1] = *(const float4*)(xp + 16 + 4 * q);
      mv[1] = *(const float4*)(mp + 16 + 4 * q);
      float4 zz = {0.f, 0.f, 0.f, 0.f};
      xv[2] = zz; mv[2] = zz;
      if (q < 3) {
        xv[2] = *(const float4*)(xp + 32 + 4 * q);
        mv[2] = *(const float4*)(mp + 32 + 4 * q);
      }
    };
    auto make_ob = [&](const float4* cx, const float4* cm, frag16* ob) {
#pragma unroll
      for (int j = 0; j < 2; ++j) {
        u32x2 u = {PK2(cx[j].x * cm[j].x, cx[j].y * cm[j].y),
                   PK2(cx[j].z * cm[j].z, cx[j].w * cm[j].w)};
        ob[j] = __builtin_bit_cast(frag16, u);
      }
      u32x2 u = {PK2(cx[2].x * cm[2].x, cx[2].y * cm[2].y),
                 PK2(cx[2].z * cm[2].z, cx[2].w * cm[2].w)};
      ob[2] = (q < 3) ? __builtin_bit_cast(frag16, u) : fgbias;  // bias row
    };

    f32x4 hc[2][4] = {};
    float4 xo[2][3], mo[2][3];
    frag16 ob[2][3];
    f32x4 pC[2][4];
#pragma unroll
    for (int it = 0; it < 2; ++it) {
      load_obs(it, T_ - 1, xo[it], mo[it]);
      make_ob(xo[it], mo[it], ob[it]);
    }
#pragma unroll
    for (int tau = 0; tau < 4; ++tau)
#pragma unroll
      for (int it = 0; it < 2; ++it)
        pC[it][tau] = MFMA16(Ai[tau][6], ob[it][2],
                             MFMA16(Ai[tau][5], ob[it][1],
                                    MFMA16(Ai[tau][4], ob[it][0], fzero)));

#pragma unroll 1
    for (int s = 0; s < T_; ++s) {
      const int t = T_ - 1 - s;
      if (t > 0) {
#pragma unroll
        for (int it = 0; it < 2; ++it) load_obs(it, t - 1, xo[it], mo[it]);
      }

      // ---- CHAIN x2, tile-inner interleave ----
      frag16 bh[2][4];
#pragma unroll
      for (int tau = 0; tau < 4; ++tau)
#pragma unroll
        for (int it = 0; it < 2; ++it) bh[it][tau] = frpk(hc[it][tau]);
#pragma unroll
      for (int tau = 0; tau < 4; ++tau) {
        f32x4 p0[2], p1[2], p2[2], p3[2];
#pragma unroll
        for (int it = 0; it < 2; ++it) p0[it] = MFMA16(Ai[tau][0], bh[it][0], pC[it][tau]);
#pragma unroll
        for (int it = 0; it < 2; ++it) p1[it] = MFMA16(Ai[tau][1], bh[it][1], fzero);
#pragma unroll
        for (int it = 0; it < 2; ++it) p2[it] = MFMA16(Ai[tau][2], bh[it][2], fzero);
#pragma unroll
        for (int it = 0; it < 2; ++it) p3[it] = MFMA16(Ai[tau][3], bh[it][3], fzero);
#pragma unroll
        for (int it = 0; it < 2; ++it)
#pragma unroll
          for (int r = 0; r < 4; ++r)
            hc[it][tau][r] = tanh_f((p0[it][r] + p1[it][r]) + (p2[it][r] + p3[it][r]));
      }

      // ---- OFF-CHAIN: next step's obs frags + pC ----
      if (t > 0) {
#pragma unroll
        for (int it = 0; it < 2; ++it) make_ob(xo[it], mo[it], ob[it]);
#pragma unroll
        for (int tau = 0; tau < 4; ++tau)
#pragma unroll
          for (int it = 0; it < 2; ++it)
            pC[it][tau] = MFMA16(Ai[tau][6], ob[it][2],
                                 MFMA16(Ai[tau][5], ob[it][1],
                                        MFMA16(Ai[tau][4], ob[it][0], fzero)));
      }
    }

    // ---- Phase 2: head, z0, KL (x2) ----
    f32x4 z[2];
#pragma unroll
    for (int it = 0; it < 2; ++it) {
      frag16 bhF[4];
#pragma unroll
      for (int tau = 0; tau < 4; ++tau) bhF[tau] = frpk(hc[it][tau]);
      f32x4 o = bo;
#pragma unroll
      for (int kc = 0; kc < 4; ++kc) o = MFMA16(Ah2o[kc], bhF[kc], o);

      float lv[4];
#pragma unroll
      for (int r = 0; r < 4; ++r)
        lv[r] = __int_as_float(__shfl(__float_as_int(o[r]), lane + 32, 64));

      f32x4 zt = {};
      if (q < 2) {
        const float4 ev = *(const float4*)(eps + (size_t)(r0 + 16 * it + c) * 8 + 4 * q);
#pragma unroll
        for (int r = 0; r < 4; ++r) {
          const float m = o[r];
          zt[r] = f4get(ev, r) * fexp(0.5f * lv[r]) + m;
          klt += -0.5f * lv[r] + (fexp(lv[r]) + m * m) * 0.5f - 0.5f;
        }
      }
      z[it] = zt;
    }
    klt += __shfl_xor(klt, 1);  klt += __shfl_xor(klt, 2);
    klt += __shfl_xor(klt, 4);  klt += __shfl_xor(klt, 8);
    klt += __shfl_xor(klt, 16); klt += __shfl_xor(klt, 32);

    __builtin_amdgcn_sched_barrier(0);  // keep phase-3 weight loads below

    // ---- Phase 3 weights (shared across tiles) ----
    frag16 A1[4], A2[4][4], A3[4];
#pragma unroll
    for (int tau = 0; tau < 4; ++tau) {
      float w1[4];
#pragma unroll
      for (int i = 0; i < 4; ++i) {
        const int k = 4 * q + i;
        w1[i] = k < 8 ? Wf1[k * 64 + 16 * tau + c] : (k == 8 ? bf1[16 * tau + c] : 0.0f);
      }
      A1[tau] = fr4(w1[0], w1[1], w1[2], w1[3]);
    }
#pragma unroll
    for (int tau = 0; tau < 4; ++tau)
#pragma unroll
      for (int kc = 0; kc < 4; ++kc) {
        float wv[4];
#pragma unroll
        for (int i = 0; i < 4; ++i) wv[i] = Wf2[(16 * kc + 4 * q + i) * 64 + 16 * tau + c];
        A2[tau][kc] = fr4(wv[0], wv[1], wv[2], wv[3]);
      }
#pragma unroll
    for (int kc = 0; kc < 4; ++kc) {
      float wv[4];
#pragma unroll
      for (int i = 0; i < 4; ++i)
        wv[i] = (c < 8) ? Wf3[(16 * kc + 4 * q + i) * 8 + c] : 0.0f;
      A3[kc] = fr4(wv[0], wv[1], wv[2], wv[3]);
    }
    f32x4 b2_[4], b3_;
#pragma unroll
    for (int tau = 0; tau < 4; ++tau)
#pragma unroll
      for (int r = 0; r < 4; ++r) b2_[tau][r] = bf2[16 * tau + 4 * q + r];
#pragma unroll
    for (int r = 0; r < 4; ++r) b3_[r] = (q < 2) ? bf3[4 * q + r] : 0.0f;

    auto build_bz = [&](f32x4 zv) -> frag16 {
      u32x2 u = {PK2(zv[0], zv[1]), PK2(zv[2], zv[3])};
      if (q == 2) { u[0] = EW(1.0f); u[1] = 0u; }
      else if (q == 3) { u[0] = 0u; u[1] = 0u; }
      return __builtin_bit_cast(frag16, u);
    };

    // feval on BOTH tiles, tile-inner interleaved (two indep dataflows).
    auto feval2 = [&](frag16 bzA, frag16 bzB, f32x4* kk) {
      frag16 bz[2] = {bzA, bzB};
      frag16 bh[2][4];
#pragma unroll
      for (int tau = 0; tau < 4; ++tau) {
        f32x4 h[2];
#pragma unroll
        for (int it = 0; it < 2; ++it) h[it] = MFMA16(A1[tau], bz[it], fzero);
#pragma unroll
        for (int it = 0; it < 2; ++it) {
#pragma unroll
          for (int r = 0; r < 4; ++r) h[it][r] = elu_f(h[it][r]);
          bh[it][tau] = frpk(h[it]);
        }
      }
      frag16 bg[2][4];
#pragma unroll
      for (int tau = 0; tau < 4; ++tau) {
        f32x4 g0[2], g1[2], g2[2], g3[2];
#pragma unroll
        for (int it = 0; it < 2; ++it) g0[it] = MFMA16(A2[tau][0], bh[it][0], b2_[tau]);
#pragma unroll
        for (int it = 0; it < 2; ++it) g1[it] = MFMA16(A2[tau][1], bh[it][1], fzero);
#pragma unroll
        for (int it = 0; it < 2; ++it) g2[it] = MFMA16(A2[tau][2], bh[it][2], fzero);
#pragma unroll
        for (int it = 0; it < 2; ++it) g3[it] = MFMA16(A2[tau][3], bh[it][3], fzero);
#pragma unroll
        for (int it = 0; it < 2; ++it) {
          f32x4 g;
#pragma unroll
          for (int r = 0; r < 4; ++r)
            g[r] = elu_f((g0[it][r] + g1[it][r]) + (g2[it][r] + g3[it][r]));
          bg[it][tau] = frpk(g);
        }
      }
      f32x4 r0_[2], r1_[2], r2_[2], r3_[2];
#pragma unroll
      for (int it = 0; it < 2; ++it) r0_[it] = MFMA16(A3[0], bg[it][0], b3_);
#pragma unroll
      for (int it = 0; it < 2; ++it) r1_[it] = MFMA16(A3[1], bg[it][1], fzero);
#pragma unroll
      for (int it = 0; it < 2; ++it) r2_[it] = MFMA16(A3[2], bg[it][2], fzero);
#pragma unroll
      for (int it = 0; it < 2; ++it) r3_[it] = MFMA16(A3[3], bg[it][3], fzero);
#pragma unroll
      for (int it = 0; it < 2; ++it)
#pragma unroll
        for (int r = 0; r < 4; ++r)
          kk[it][r] = (r0_[it][r] + r1_[it][r]) + (r2_[it][r] + r3_[it][r]);
    };

    const float dt = 1.0f / (float)(T_ - 1);
    const float hdt = 0.5f * dt;

#pragma unroll 1
    for (int t = 0; t < T_; ++t) {
      // ---- produce z_t (both tiles) to ring; in-order DS pipe + compiler
      // barrier pins data-before-flag; no waitcnt on the chain. ----
      if (q < 2) {
#pragma unroll
        for (int it = 0; it < 2; ++it) {
          u32x2 v = {PK2(z[it][0], z[it][1]), PK2(z[it][2], z[it][3])};
          *(u32x2*)(ring + (t * 64 + it * 32 + c * 2 + q) * 2) = v;
        }
      }
      asm volatile("" ::: "memory");
      if (lane == 0) ((volatile uint32_t*)flags)[t] = 1u;

      // ---- RK4 advance, both tiles interleaved ----
      if (t < T_ - 1) {
        f32x4 k1[2], k2[2], k3[2], k4[2], zt[2];
        feval2(build_bz(z[0]), build_bz(z[1]), k1);
#pragma unroll
        for (int it = 0; it < 2; ++it)
#pragma unroll
          for (int r = 0; r < 4; ++r) zt[it][r] = z[it][r] + hdt * k1[it][r];
        feval2(build_bz(zt[0]), build_bz(zt[1]), k2);
#pragma unroll
        for (int it = 0; it < 2; ++it)
#pragma unroll
          for (int r = 0; r < 4; ++r) zt[it][r] = z[it][r] + hdt * k2[it][r];
        feval2(build_bz(zt[0]), build_bz(zt[1]), k3);
#pragma unroll
        for (int it = 0; it < 2; ++it)
#pragma unroll
          for (int r = 0; r < 4; ++r) zt[it][r] = z[it][r] + dt * k3[it][r];
        feval2(build_bz(zt[0]), build_bz(zt[1]), k4);
#pragma unroll
        for (int it = 0; it < 2; ++it)
#pragma unroll
          for (int r = 0; r < 4; ++r)
            z[it][r] += (dt / 6.0f) * (k1[it][r] + 2.0f * (k2[it][r] + k3[it][r]) + k4[it][r]);
      }
    }
  } else {
    // ==================== WAVE 1: decoder + NLL (both tiles) ====================
    frag16 Ad1[4], Ad2[3][4];
#pragma unroll
    for (int tau = 0; tau < 4; ++tau) {
      float wd[4];
#pragma unroll
      for (int i = 0; i < 4; ++i) {
        const int k = 4 * q + i;
        wd[i] = k < 8 ? Wd1[k * 64 + 16 * tau + c] : (k == 8 ? bd1[16 * tau + c] : 0.0f);
      }
      Ad1[tau] = fr4(wd[0], wd[1], wd[2], wd[3]);
    }
#pragma unroll
    for (int tau = 0; tau < 3; ++tau)
#pragma unroll
      for (int kc = 0; kc < 4; ++kc) {
        const int m = 16 * tau + c;
        float wv[4];
#pragma unroll
        for (int i = 0; i < 4; ++i)
          wv[i] = (m < 44) ? Wd2[(16 * kc + 4 * q + i) * 44 + m] : 0.0f;
        Ad2[tau][kc] = fr4(wv[0], wv[1], wv[2], wv[3]);
      }
    f32x4 bd2_[3];
#pragma unroll
    for (int tau = 0; tau < 3; ++tau)
#pragma unroll
      for (int r = 0; r < 4; ++r) {
        const int d = 16 * tau + 4 * q + r;
        bd2_[tau][r] = (d < 44) ? bd2[d] : 0.0f;
      }

    float qacc = 0.0f;
    volatile uint32_t* vf = flags;

#pragma unroll 1
    for (int t = 0; t < T_; ++t) {
      float4 xc[2][3], mc[2][3];
#pragma unroll
      for (int it = 0; it < 2; ++it)
#pragma unroll
        for (int tau = 0; tau < 3; ++tau) {
          const int d0 = 16 * tau + 4 * q;
          if (d0 < 44) {
            const size_t off = (size_t)(r0 + 16 * it + c) * T_ * D_ + (size_t)t * D_ + d0;
            xc[it][tau] = *(const float4*)(x + off);
            mc[it][tau] = *(const float4*)(mask + off);
          } else {
            float4 zz = {0.f, 0.f, 0.f, 0.f};
            xc[it][tau] = zz; mc[it][tau] = zz;
          }
        }

      while (vf[t] == 0u) __builtin_amdgcn_s_sleep(1);
      asm volatile("" ::: "memory");

      frag16 bz[2];
#pragma unroll
      for (int it = 0; it < 2; ++it) {
        u32x2 u = {0u, 0u};
        if (q < 2) u = *(const u32x2*)(ring + (t * 64 + it * 32 + c * 2 + q) * 2);
        else if (q == 2) u[0] = EW(1.0f);
        bz[it] = __builtin_bit_cast(frag16, u);
      }

      frag16 bhd[2][4];
#pragma unroll
      for (int tau = 0; tau < 4; ++tau) {
        f32x4 hd[2];
#pragma unroll
        for (int it = 0; it < 2; ++it) hd[it] = MFMA16(Ad1[tau], bz[it], fzero);
#pragma unroll
        for (int it = 0; it < 2; ++it) {
#pragma unroll
          for (int r = 0; r < 4; ++r) hd[it][r] = fmaxf(hd[it][r], 0.0f);
          bhd[it][tau] = frpk(hd[it]);
        }
      }
#pragma unroll
      for (int tau = 0; tau < 3; ++tau) {
        f32x4 p0[2], p1[2], p2[2], p3[2];
#pragma unroll
        for (int it = 0; it < 2; ++it) p0[it] = MFMA16(Ad2[tau][0], bhd[it][0], bd2_[tau]);
#pragma unroll
        for (int it = 0; it < 2; ++it) p1[it] = MFMA16(Ad2[tau][1], bhd[it][1], fzero);
#pragma unroll
        for (int it = 0; it < 2; ++it) p2[it] = MFMA16(Ad2[tau][2], bhd[it][2], fzero);
#pragma unroll
        for (int it = 0; it < 2; ++it) p3[it] = MFMA16(Ad2[tau][3], bhd[it][3], fzero);
        if (16 * tau + 4 * q < 44) {
#pragma unroll
          for (int it = 0; it < 2; ++it)
#pragma unroll
            for (int r = 0; r < 4; ++r) {
              const float p = (p0[it][r] + p1[it][r]) + (p2[it][r] + p3[it][r]);
              const float xa = f4get(xc[it][tau], r), ma = f4get(mc[it][tau], r);
              const float mx = xa * ma;
              const float upd = (mx != 0.0f) ? mx : p;
              const float df = xa - upd;
              qacc += df * df;
            }
        }
      }
    }

    float tot = qacc * (0.5f / 0.09f);
    tot += __shfl_xor(tot, 1);  tot += __shfl_xor(tot, 2);
    tot += __shfl_xor(tot, 4);  tot += __shfl_xor(tot, 8);
    tot += __shfl_xor(tot, 16); tot += __shfl_xor(tot, 32);
    if (lane == 0) sse_sh = tot;
  }

  __syncthreads();  // merge the two waves' partials
  if (tid == 0) part[blockIdx.x] = sse_sh + klt;
}

// =================== final reduction: 256 partials -> loss ===================
__global__ __launch_bounds__(256) void reduce_kernel(const float* __restrict__ part,
                                                     float* __restrict__ out) {
  __shared__ float s[4];
  const int tid = threadIdx.x;
  float v = part[tid];
  v += __shfl_xor(v, 1);  v += __shfl_xor(v, 2);
  v += __shfl_xor(v, 4);  v += __shfl_xor(v, 8);
  v += __shfl_xor(v, 16); v += __shfl_xor(v, 32);
  if ((tid & 63) == 0) s[tid >> 6] = v;
  __syncthreads();
  if (tid == 0) {
    float acc = 0.0f;
#pragma unroll
    for (int i = 0; i < 4; ++i) acc += s[i];
    const float c0 = 0.28503427112126353f;  // -0.5*(log(2pi)+2*log(0.3))
    out[0] = acc * (1.0f / (float)B_) - (float)(T_ * D_) * c0;
  }
}

extern "C" void kernel_launch(void* const* d_in, const int* in_sizes, int n_in,
                              void* d_out, int out_size, void* d_ws, size_t ws_size,
                              hipStream_t stream) {
  const float* x    = (const float*)d_in[0];
  const float* mask = (const float*)d_in[1];
  const float* eps  = (const float*)d_in[2];
  const float* Wi2h = (const float*)d_in[3];
  const float* bi2h = (const float*)d_in[4];
  const float* Wh2o = (const float*)d_in[5];
  const float* bh2o = (const float*)d_in[6];
  const float* Wf1  = (const float*)d_in[7];
  const float* bf1  = (const float*)d_in[8];
  const float* Wf2  = (const float*)d_in[9];
  const float* bf2  = (const float*)d_in[10];
  const float* Wf3  = (const float*)d_in[11];
  const float* bf3  = (const float*)d_in[12];
  const float* Wd1  = (const float*)d_in[13];
  const float* bd1  = (const float*)d_in[14];
  const float* Wd2  = (const float*)d_in[15];
  const float* bd2  = (const float*)d_in[16];

  float* loss = (float*)d_out;
  float* part = (float*)d_ws;  // 256 floats used

  fused_kernel<<<dim3(B_ / 32), dim3(128), 0, stream>>>(
      x, mask, eps, Wi2h, bi2h, Wh2o, bh2o, Wf1, bf1, Wf2, bf2, Wf3, bf3,
      Wd1, bd1, Wd2, bd2, part);
  reduce_kernel<<<dim3(1), dim3(256), 0, stream>>>(part, loss);
}

// Round 9
// 681.246 us; speedup vs baseline: 1.5813x; 1.5813x over previous
//
#include <hip/hip_runtime.h>
#include <stdint.h>

// LatentODE fused: B=8192, T=100, D=44, NH=64, L=8.
// 512 blocks x 128 thr. Wave0 = minimal serial chain; wave1 = helper.
// NEW (r9): phase-1 obs pipeline (loads, mask-mul, packing, 3-MFMA obs
// subtree pC) moved to wave1 (idle during phase 1 before), delivered as
// ready f32 pC[4] frags via an 8-slot LDS ring (producer counter w1prog,
// consumer counter w0cons, batch-spin every 4 steps, both sides prefetch).
// Wave0 phase-1 step = 4 ds_read_b128 + 4 MFMA + tanh + pack only.
// Phase 3 unchanged from r6 (trees, in-lane K=16 boundaries, z-ring to
// wave1's decoder+NLL). pC bit-identical f32 -> numerics unchanged.

constexpr int B_ = 8192, T_ = 100, D_ = 44, NH_ = 64, L_ = 8;

typedef float f32x4 __attribute__((ext_vector_type(4)));
typedef uint32_t u32x2 __attribute__((ext_vector_type(2)));

// ---- K=16 MFMA with __has_builtin fallback chain ----
#if __has_builtin(__builtin_amdgcn_mfma_f32_16x16x16bf16_1k)
typedef short frag16 __attribute__((ext_vector_type(4)));
#define MFMA16(a, b, c) __builtin_amdgcn_mfma_f32_16x16x16bf16_1k(a, b, c, 0, 0, 0)
#define USE_F16 0
#elif __has_builtin(__builtin_amdgcn_mfma_f32_16x16x16_bf16_1k)
typedef short frag16 __attribute__((ext_vector_type(4)));
#define MFMA16(a, b, c) __builtin_amdgcn_mfma_f32_16x16x16_bf16_1k(a, b, c, 0, 0, 0)
#define USE_F16 0
#elif __has_builtin(__builtin_amdgcn_mfma_f32_16x16x16_bf16)
typedef __bf16 frag16 __attribute__((ext_vector_type(4)));
#define MFMA16(a, b, c) __builtin_amdgcn_mfma_f32_16x16x16_bf16(a, b, c, 0, 0, 0)
#define USE_F16 0
#else
typedef _Float16 frag16 __attribute__((ext_vector_type(4)));
#define MFMA16(a, b, c) __builtin_amdgcn_mfma_f32_16x16x16f16(a, b, c, 0, 0, 0)
#define USE_F16 1
#endif

__device__ __forceinline__ float fexp2(float x) { return __builtin_amdgcn_exp2f(x); }
__device__ __forceinline__ float frcp(float x) { return __builtin_amdgcn_rcpf(x); }
__device__ __forceinline__ float fexp(float x) { return fexp2(x * 1.44269504088896341f); }
__device__ __forceinline__ float tanh_f(float x) {
  float e = fexp2(x * 2.88539008177792681f);
  return 1.0f - 2.0f * frcp(e + 1.0f);
}
__device__ __forceinline__ float elu_f(float x) { return x > 0.0f ? x : (fexp(x) - 1.0f); }

__device__ __forceinline__ uint32_t EW(float v) {
#if USE_F16
  return (uint32_t)__builtin_bit_cast(unsigned short, (_Float16)v);
#else
  return (uint32_t)__builtin_bit_cast(unsigned short, (__bf16)v);
#endif
}
__device__ __forceinline__ uint32_t PK2(float lo, float hi) { return EW(lo) | (EW(hi) << 16); }
__device__ __forceinline__ frag16 fr4(float a, float b, float c, float d) {
  u32x2 u = {PK2(a, b), PK2(c, d)};
  return __builtin_bit_cast(frag16, u);
}
__device__ __forceinline__ frag16 frpk(f32x4 v) {
  u32x2 u = {PK2(v[0], v[1]), PK2(v[2], v[3])};
  return __builtin_bit_cast(frag16, u);
}
__device__ __forceinline__ float f4get(const float4& f, int i) {
  return i == 0 ? f.x : (i == 1 ? f.y : (i == 2 ? f.z : f.w));
}

__global__ __launch_bounds__(128) void fused_kernel(
    const float* __restrict__ x, const float* __restrict__ mask,
    const float* __restrict__ eps,
    const float* __restrict__ Wi2h, const float* __restrict__ bi2h,
    const float* __restrict__ Wh2o, const float* __restrict__ bh2o,
    const float* __restrict__ Wf1, const float* __restrict__ bf1,
    const float* __restrict__ Wf2, const float* __restrict__ bf2,
    const float* __restrict__ Wf3, const float* __restrict__ bf3,
    const float* __restrict__ Wd1, const float* __restrict__ bd1,
    const float* __restrict__ Wd2, const float* __restrict__ bd2,
    float* __restrict__ part) {
  const int tid = threadIdx.x;
  const int wid = tid >> 6;
  const int lane = tid & 63;
  const int c = lane & 15, q = lane >> 4;
  const int r0 = blockIdx.x * 16;
  const f32x4 fzero = {0.f, 0.f, 0.f, 0.f};

  // z-ring: [t][c*2+q] u32x2 (bf16-packed z rows 4q..4q+3, col c), q<2.
  __shared__ __align__(16) uint32_t ring[6400];   // 25.6 KB
  // pC ring: 8 slots x (4 tau x 64 lanes x f32x4). Layout slot*1024 +
  // tau*256 + lane*4 floats -> lane stride 16B: 2 lanes/bank (free).
  __shared__ __align__(16) float pcring[8192];    // 32 KB
  __shared__ uint32_t flags[104];
  __shared__ uint32_t w1prog;  // pC slots produced (wave1)
  __shared__ uint32_t w0cons;  // pC slots consumed (wave0)
  __shared__ float sse_sh;

  if (tid < 104) flags[tid] = 0u;
  if (tid == 0) { w1prog = 0u; w0cons = 0u; }
  __syncthreads();

  float klt = 0.0f;

  if (wid == 0) {
    // ==================== WAVE 0: serial chain only ====================
    // Phase-1 weights: h-part only (kc 0..3); obs part lives in wave1.
    frag16 Ah[4][4];
#pragma unroll
    for (int tau = 0; tau < 4; ++tau)
#pragma unroll
      for (int kc = 0; kc < 4; ++kc) {
        const int m = 16 * tau + c;
        float wv[4];
#pragma unroll
        for (int i = 0; i < 4; ++i) wv[i] = Wi2h[(44 + 16 * kc + 4 * q + i) * 64 + m];
        Ah[tau][kc] = fr4(wv[0], wv[1], wv[2], wv[3]);
      }
    frag16 Ah2o[4];
#pragma unroll
    for (int kc = 0; kc < 4; ++kc) {
      float wv[4];
#pragma unroll
      for (int i = 0; i < 4; ++i) wv[i] = Wh2o[(16 * kc + 4 * q + i) * 16 + c];
      Ah2o[kc] = fr4(wv[0], wv[1], wv[2], wv[3]);
    }
    f32x4 bo;
#pragma unroll
    for (int r = 0; r < 4; ++r) bo[r] = bh2o[4 * q + r];

    volatile uint32_t* vprod = &w1prog;
    volatile uint32_t* vcons = &w0cons;

    // preload pC slot 0
    while (*vprod < 1u) __builtin_amdgcn_s_sleep(1);
    asm volatile("" ::: "memory");
    f32x4 pcur[4], pnext[4];
#pragma unroll
    for (int tau = 0; tau < 4; ++tau)
      pcur[tau] = *(const f32x4*)(pcring + tau * 256 + lane * 4);
    if (lane == 0) *vcons = 1u;

    f32x4 hc[4] = {};
#pragma unroll 1
    for (int s = 0; s < T_; ++s) {
      // batched producer spin: every 4 steps ensure slots s+1..s+4 ready
      if ((s & 3) == 0) {
        const uint32_t need = (uint32_t)((s + 5 > T_) ? T_ : s + 5);
        while (*vprod < need) __builtin_amdgcn_s_sleep(1);
        asm volatile("" ::: "memory");
      }
      if (s < T_ - 1) {  // prefetch next slot; consumed next iteration
        const int sl = (s + 1) & 7;
#pragma unroll
        for (int tau = 0; tau < 4; ++tau)
          pnext[tau] = *(const f32x4*)(pcring + sl * 1024 + tau * 256 + lane * 4);
        if (lane == 0) *vcons = (uint32_t)(s + 2);
      }

      // ---- CHAIN: pack h -> 4 indep MFMA (+pC C-in) -> adds -> tanh ----
      frag16 bh[4];
#pragma unroll
      for (int tau = 0; tau < 4; ++tau) bh[tau] = frpk(hc[tau]);
#pragma unroll
      for (int tau = 0; tau < 4; ++tau) {
        f32x4 p0 = MFMA16(Ah[tau][0], bh[0], pcur[tau]);
        f32x4 p1 = MFMA16(Ah[tau][1], bh[1], fzero);
        f32x4 p2 = MFMA16(Ah[tau][2], bh[2], fzero);
        f32x4 p3 = MFMA16(Ah[tau][3], bh[3], fzero);
#pragma unroll
        for (int r = 0; r < 4; ++r)
          hc[tau][r] = tanh_f((p0[r] + p1[r]) + (p2[r] + p3[r]));
      }
#pragma unroll
      for (int tau = 0; tau < 4; ++tau) pcur[tau] = pnext[tau];
    }

    // ---- Phase 2: head, z0, KL ----
    frag16 bhF[4];
#pragma unroll
    for (int tau = 0; tau < 4; ++tau) bhF[tau] = frpk(hc[tau]);
    f32x4 o = bo;
#pragma unroll
    for (int kc = 0; kc < 4; ++kc) o = MFMA16(Ah2o[kc], bhF[kc], o);

    float lv[4];
#pragma unroll
    for (int r = 0; r < 4; ++r)
      lv[r] = __int_as_float(__shfl(__float_as_int(o[r]), lane + 32, 64));

    f32x4 z = {};
    if (q < 2) {
      const float4 ev = *(const float4*)(eps + (size_t)(r0 + c) * 8 + 4 * q);
#pragma unroll
      for (int r = 0; r < 4; ++r) {
        const float m = o[r];
        z[r] = f4get(ev, r) * fexp(0.5f * lv[r]) + m;
        klt += -0.5f * lv[r] + (fexp(lv[r]) + m * m) * 0.5f - 0.5f;
      }
    }
    klt += __shfl_xor(klt, 1);  klt += __shfl_xor(klt, 2);
    klt += __shfl_xor(klt, 4);  klt += __shfl_xor(klt, 8);
    klt += __shfl_xor(klt, 16); klt += __shfl_xor(klt, 32);

    __builtin_amdgcn_sched_barrier(0);  // keep phase-3 weight loads below

    // ---- Phase 3 weights (f-net only; decoder lives in wave 1) ----
    frag16 A1[4], A2[4][4], A3[4];
#pragma unroll
    for (int tau = 0; tau < 4; ++tau) {
      float w1[4];
#pragma unroll
      for (int i = 0; i < 4; ++i) {
        const int k = 4 * q + i;  // z rows 0..7, bias at k=8
        w1[i] = k < 8 ? Wf1[k * 64 + 16 * tau + c] : (k == 8 ? bf1[16 * tau + c] : 0.0f);
      }
      A1[tau] = fr4(w1[0], w1[1], w1[2], w1[3]);
    }
#pragma unroll
    for (int tau = 0; tau < 4; ++tau)
#pragma unroll
      for (int kc = 0; kc < 4; ++kc) {
        float wv[4];
#pragma unroll
        for (int i = 0; i < 4; ++i) wv[i] = Wf2[(16 * kc + 4 * q + i) * 64 + 16 * tau + c];
        A2[tau][kc] = fr4(wv[0], wv[1], wv[2], wv[3]);
      }
#pragma unroll
    for (int kc = 0; kc < 4; ++kc) {
      float wv[4];
#pragma unroll
      for (int i = 0; i < 4; ++i)
        wv[i] = (c < 8) ? Wf3[(16 * kc + 4 * q + i) * 8 + c] : 0.0f;  // M=8 pad
      A3[kc] = fr4(wv[0], wv[1], wv[2], wv[3]);
    }
    f32x4 b2_[4], b3_;
#pragma unroll
    for (int tau = 0; tau < 4; ++tau)
#pragma unroll
      for (int r = 0; r < 4; ++r) b2_[tau][r] = bf2[16 * tau + 4 * q + r];
#pragma unroll
    for (int r = 0; r < 4; ++r) b3_[r] = (q < 2) ? bf3[4 * q + r] : 0.0f;

    auto build_bz = [&](f32x4 zv) -> frag16 {
      u32x2 u = {PK2(zv[0], zv[1]), PK2(zv[2], zv[3])};
      if (q == 2) { u[0] = EW(1.0f); u[1] = 0u; }
      else if (q == 3) { u[0] = 0u; u[1] = 0u; }
      return __builtin_bit_cast(frag16, u);
    };

    // feval: depth-1 MFMA trees (chain = 3 MFMA hops total)
    auto feval = [&](frag16 bz) -> f32x4 {
      frag16 bh[4];
#pragma unroll
      for (int tau = 0; tau < 4; ++tau) {
        f32x4 h = MFMA16(A1[tau], bz, fzero);
#pragma unroll
        for (int r = 0; r < 4; ++r) h[r] = elu_f(h[r]);
        bh[tau] = frpk(h);
      }
      frag16 bg[4];
#pragma unroll
      for (int tau = 0; tau < 4; ++tau) {
        f32x4 g0 = MFMA16(A2[tau][0], bh[0], b2_[tau]);
        f32x4 g1 = MFMA16(A2[tau][1], bh[1], fzero);
        f32x4 g2 = MFMA16(A2[tau][2], bh[2], fzero);
        f32x4 g3 = MFMA16(A2[tau][3], bh[3], fzero);
        f32x4 g;
#pragma unroll
        for (int r = 0; r < 4; ++r) g[r] = elu_f((g0[r] + g1[r]) + (g2[r] + g3[r]));
        bg[tau] = frpk(g);
      }
      f32x4 r0_ = MFMA16(A3[0], bg[0], b3_);
      f32x4 r1_ = MFMA16(A3[1], bg[1], fzero);
      f32x4 r2_ = MFMA16(A3[2], bg[2], fzero);
      f32x4 r3_ = MFMA16(A3[3], bg[3], fzero);
      f32x4 rr;
#pragma unroll
      for (int r = 0; r < 4; ++r) rr[r] = (r0_[r] + r1_[r]) + (r2_[r] + r3_[r]);
      return rr;
    };

    const float dt = 1.0f / (float)(T_ - 1);
    const float hdt = 0.5f * dt;

#pragma unroll 1
    for (int t = 0; t < T_; ++t) {
      // produce z_t to ring; same-wave in-order DS pipe, no waitcnt.
      if (q < 2) {
        u32x2 v = {PK2(z[0], z[1]), PK2(z[2], z[3])};
        *(u32x2*)(ring + (t * 32 + c * 2 + q) * 2) = v;
      }
      asm volatile("" ::: "memory");
      if (lane == 0) ((volatile uint32_t*)flags)[t] = 1u;

      if (t < T_ - 1) {
        f32x4 k1 = feval(build_bz(z));
        f32x4 zt;
#pragma unroll
        for (int r = 0; r < 4; ++r) zt[r] = z[r] + hdt * k1[r];
        f32x4 k2 = feval(build_bz(zt));
#pragma unroll
        for (int r = 0; r < 4; ++r) zt[r] = z[r] + hdt * k2[r];
        f32x4 k3 = feval(build_bz(zt));
#pragma unroll
        for (int r = 0; r < 4; ++r) zt[r] = z[r] + dt * k3[r];
        f32x4 k4 = feval(build_bz(zt));
#pragma unroll
        for (int r = 0; r < 4; ++r)
          z[r] += (dt / 6.0f) * (k1[r] + 2.0f * (k2[r] + k3[r]) + k4[r]);
      }
    }
  } else {
    // ==================== WAVE 1: obs producer, then decoder+NLL =========
    const frag16 fgbias = fr4(1.0f, 0.f, 0.f, 0.f);

    // obs-part weights (kc 4..6 of the state matrix, incl bias row 108)
    frag16 Ao[4][3];
#pragma unroll
    for (int tau = 0; tau < 4; ++tau)
#pragma unroll
      for (int kc = 0; kc < 3; ++kc) {
        const int m = 16 * tau + c;
        float wv[4];
#pragma unroll
        for (int i = 0; i < 4; ++i) {
          const int k = 64 + 16 * kc + 4 * q + i;
          float v = 0.0f;
          if (k < 108) v = Wi2h[(k - 64) * 64 + m];
          else if (k == 108) v = bi2h[m];
          wv[i] = v;
        }
        Ao[tau][kc] = fr4(wv[0], wv[1], wv[2], wv[3]);
      }

    const float* xrowbase = x + (size_t)(r0 + c) * T_ * D_;
    const float* mrowbase = mask + (size_t)(r0 + c) * T_ * D_;

    auto load_obs = [&](int t, float4* xv, float4* mv) {
      const float* xp = xrowbase + (size_t)t * D_;
      const float* mp = mrowbase + (size_t)t * D_;
      xv[0] = *(const float4*)(xp + 4 * q);
      mv[0] = *(const float4*)(mp + 4 * q);
      xv[1] = *(const float4*)(xp + 16 + 4 * q);
      mv[1] = *(const float4*)(mp + 16 + 4 * q);
      float4 zz = {0.f, 0.f, 0.f, 0.f};
      xv[2] = zz; mv[2] = zz;
      if (q < 3) {
        xv[2] = *(const float4*)(xp + 32 + 4 * q);
        mv[2] = *(const float4*)(mp + 32 + 4 * q);
      }
    };
    auto make_ob = [&](const float4* cx, const float4* cm, frag16* ob) {
#pragma unroll
      for (int j = 0; j < 2; ++j) {
        u32x2 u = {PK2(cx[j].x * cm[j].x, cx[j].y * cm[j].y),
                   PK2(cx[j].z * cm[j].z, cx[j].w * cm[j].w)};
        ob[j] = __builtin_bit_cast(frag16, u);
      }
      u32x2 u = {PK2(cx[2].x * cm[2].x, cx[2].y * cm[2].y),
                 PK2(cx[2].z * cm[2].z, cx[2].w * cm[2].w)};
      ob[2] = (q < 3) ? __builtin_bit_cast(frag16, u) : fgbias;  // bias row
    };

    volatile uint32_t* vcons = &w0cons;
    volatile uint32_t* vprod = &w1prog;

    {
      float4 xo[3], mo[3];
      load_obs(T_ - 1, xo, mo);
#pragma unroll 1
      for (int s1 = 0; s1 < T_; ++s1) {
        const int t = T_ - 1 - s1;
        float4 cx[3], cm[3];
#pragma unroll
        for (int j = 0; j < 3; ++j) { cx[j] = xo[j]; cm[j] = mo[j]; }
        if (t > 0) load_obs(t - 1, xo, mo);  // prefetch next step

        frag16 ob[3];
        make_ob(cx, cm, ob);
        f32x4 pc[4];
#pragma unroll
        for (int tau = 0; tau < 4; ++tau)
          pc[tau] = MFMA16(Ao[tau][2], ob[2],
                           MFMA16(Ao[tau][1], ob[1],
                                  MFMA16(Ao[tau][0], ob[0], fzero)));

        // throttle: never more than 8 slots ahead of wave0
        while ((uint32_t)s1 >= *vcons + 8u) __builtin_amdgcn_s_sleep(1);
        asm volatile("" ::: "memory");
        const int sl = s1 & 7;
#pragma unroll
        for (int tau = 0; tau < 4; ++tau)
          *(f32x4*)(pcring + sl * 1024 + tau * 256 + lane * 4) = pc[tau];
        asm volatile("" ::: "memory");  // data before counter (in-order DS)
        if (lane == 0) *vprod = (uint32_t)(s1 + 1);
      }
    }

    // ---- decoder weights (loaded after pC production; registers freed) ----
    frag16 Ad1[4], Ad2[3][4];
#pragma unroll
    for (int tau = 0; tau < 4; ++tau) {
      float wd[4];
#pragma unroll
      for (int i = 0; i < 4; ++i) {
        const int k = 4 * q + i;
        wd[i] = k < 8 ? Wd1[k * 64 + 16 * tau + c] : (k == 8 ? bd1[16 * tau + c] : 0.0f);
      }
      Ad1[tau] = fr4(wd[0], wd[1], wd[2], wd[3]);
    }
#pragma unroll
    for (int tau = 0; tau < 3; ++tau)
#pragma unroll
      for (int kc = 0; kc < 4; ++kc) {
        const int m = 16 * tau + c;
        float wv[4];
#pragma unroll
        for (int i = 0; i < 4; ++i)
          wv[i] = (m < 44) ? Wd2[(16 * kc + 4 * q + i) * 44 + m] : 0.0f;
        Ad2[tau][kc] = fr4(wv[0], wv[1], wv[2], wv[3]);
      }
    f32x4 bd2_[3];
#pragma unroll
    for (int tau = 0; tau < 3; ++tau)
#pragma unroll
      for (int r = 0; r < 4; ++r) {
        const int d = 16 * tau + 4 * q + r;
        bd2_[tau][r] = (d < 44) ? bd2[d] : 0.0f;
      }

    float qacc = 0.0f;
    volatile uint32_t* vf = flags;

#pragma unroll 1
    for (int t = 0; t < T_; ++t) {
      float4 xc[3], mc[3];
#pragma unroll
      for (int tau = 0; tau < 3; ++tau) {
        const int d0 = 16 * tau + 4 * q;
        if (d0 < 44) {
          const size_t off = (size_t)(r0 + c) * T_ * D_ + (size_t)t * D_ + d0;
          xc[tau] = *(const float4*)(x + off);
          mc[tau] = *(const float4*)(mask + off);
        } else {
          float4 zz = {0.f, 0.f, 0.f, 0.f};
          xc[tau] = zz; mc[tau] = zz;
        }
      }

      while (vf[t] == 0u) __builtin_amdgcn_s_sleep(1);
      asm volatile("" ::: "memory");  // no hoisting of ring read above spin

      frag16 bz;
      {
        u32x2 u = {0u, 0u};
        if (q < 2) u = *(const u32x2*)(ring + (t * 32 + c * 2 + q) * 2);
        else if (q == 2) u[0] = EW(1.0f);
        bz = __builtin_bit_cast(frag16, u);
      }

      frag16 bhd[4];
#pragma unroll
      for (int tau = 0; tau < 4; ++tau) {
        f32x4 hd = MFMA16(Ad1[tau], bz, fzero);
#pragma unroll
        for (int r = 0; r < 4; ++r) hd[r] = fmaxf(hd[r], 0.0f);
        bhd[tau] = frpk(hd);
      }
#pragma unroll
      for (int tau = 0; tau < 3; ++tau) {
        f32x4 p0 = MFMA16(Ad2[tau][0], bhd[0], bd2_[tau]);
        f32x4 p1 = MFMA16(Ad2[tau][1], bhd[1], fzero);
        f32x4 p2 = MFMA16(Ad2[tau][2], bhd[2], fzero);
        f32x4 p3 = MFMA16(Ad2[tau][3], bhd[3], fzero);
        if (16 * tau + 4 * q < 44) {
#pragma unroll
          for (int r = 0; r < 4; ++r) {
            const float p = (p0[r] + p1[r]) + (p2[r] + p3[r]);
            const float xa = f4get(xc[tau], r), ma = f4get(mc[tau], r);
            const float mx = xa * ma;
            const float upd = (mx != 0.0f) ? mx : p;
            const float df = xa - upd;
            qacc += df * df;
          }
        }
      }
    }

    float tot = qacc * (0.5f / 0.09f);
    tot += __shfl_xor(tot, 1);  tot += __shfl_xor(tot, 2);
    tot += __shfl_xor(tot, 4);  tot += __shfl_xor(tot, 8);
    tot += __shfl_xor(tot, 16); tot += __shfl_xor(tot, 32);
    if (lane == 0) sse_sh = tot;
  }

  __syncthreads();  // merge the two waves' partials
  if (tid == 0) part[blockIdx.x] = sse_sh + klt;
}

// =================== final reduction: 512 partials -> loss ===================
__global__ __launch_bounds__(512) void reduce_kernel(const float* __restrict__ part,
                                                     float* __restrict__ out) {
  __shared__ float s[8];
  const int tid = threadIdx.x;
  float v = part[tid];
  v += __shfl_xor(v, 1);  v += __shfl_xor(v, 2);
  v += __shfl_xor(v, 4);  v += __shfl_xor(v, 8);
  v += __shfl_xor(v, 16); v += __shfl_xor(v, 32);
  if ((tid & 63) == 0) s[tid >> 6] = v;
  __syncthreads();
  if (tid == 0) {
    float acc = 0.0f;
#pragma unroll
    for (int i = 0; i < 8; ++i) acc += s[i];
    const float c0 = 0.28503427112126353f;  // -0.5*(log(2pi)+2*log(0.3))
    out[0] = acc * (1.0f / (float)B_) - (float)(T_ * D_) * c0;
  }
}

extern "C" void kernel_launch(void* const* d_in, const int* in_sizes, int n_in,
                              void* d_out, int out_size, void* d_ws, size_t ws_size,
                              hipStream_t stream) {
  const float* x    = (const float*)d_in[0];
  const float* mask = (const float*)d_in[1];
  const float* eps  = (const float*)d_in[2];
  const float* Wi2h = (const float*)d_in[3];
  const float* bi2h = (const float*)d_in[4];
  const float* Wh2o = (const float*)d_in[5];
  const float* bh2o = (const float*)d_in[6];
  const float* Wf1  = (const float*)d_in[7];
  const float* bf1  = (const float*)d_in[8];
  const float* Wf2  = (const float*)d_in[9];
  const float* bf2  = (const float*)d_in[10];
  const float* Wf3  = (const float*)d_in[11];
  const float* bf3  = (const float*)d_in[12];
  const float* Wd1  = (const float*)d_in[13];
  const float* bd1  = (const float*)d_in[14];
  const float* Wd2  = (const float*)d_in[15];
  const float* bd2  = (const float*)d_in[16];

  float* loss = (float*)d_out;
  float* part = (float*)d_ws;  // 512 floats

  fused_kernel<<<dim3(B_ / 16), dim3(128), 0, stream>>>(
      x, mask, eps, Wi2h, bi2h, Wh2o, bh2o, Wf1, bf1, Wf2, bf2, Wf3, bf3,
      Wd1, bd1, Wd2, bd2, part);
  reduce_kernel<<<dim3(1), dim3(512), 0, stream>>>(part, loss);
}